// Round 13
// baseline (165.219 us; speedup 1.0000x reference)
//
#include <hip/hip_runtime.h>

// SSIM loss, R15 = R14 with the OOB clamp bug fixed. R14 post-mortem: core
// dump — the "unconditional clamped" load only clamped colh<0; colh reaches
// 512 (bx=7, w=3, grp8=24) and with rc=511, bc=47 the float4 pair reads past
// the end of sr/hr -> fault. Fix: cc clamped to [0, IMG_W-8] (504, still 8-
// aligned); cok masks those lanes to zero at frag build (same as R13 guard,
// identical arithmetic).
//
// R14 design (untested, not refuted): R13 structure (no X staging, Ht-only
// LDS, wave-decoupled, ZERO in-loop barriers) + 1-tile-deep register
// prefetch:
//  - all 12 next-tile float4 loads issued at top of tile compute (48 VGPR),
//    pinned by sched_barrier(0); nothing ever drains vmcnt -> loads ride the
//    whole ~650cy tile compute.
//  - loads UNCONDITIONAL via clamped row/col addresses (hoistable); OOB lanes
//    zero-masked at frag build (identical arithmetic -> absmax unchanged).
//  - per-Mt transpose-store right after its 4 MFMAs: acc footprint 16 regs.
//    Peak ~119 VGPR -> __launch_bounds__(256,4).
//  - cur<-nxt register rotate at tile end (~48 movs, ~3%).
// Retained: one-k-step band MFMA, LDS g-table, rs compensation, TH=32/TW=64,
// HTP=56, persistent 1280 blocks, bc += 10.

typedef __attribute__((ext_vector_type(2))) float  f32x2;
typedef __attribute__((ext_vector_type(4))) float  f32x4;
typedef __fp16 f16;
typedef __attribute__((ext_vector_type(2))) __fp16 h2v;
typedef __attribute__((ext_vector_type(4))) __fp16 h4;
typedef __attribute__((ext_vector_type(8))) __fp16 h8;

constexpr int IMG_H = 512;
constexpr int IMG_W = 512;
constexpr int PL    = IMG_H * IMG_W;
constexpr int NBC   = 48;
constexpr int TW    = 64;
constexpr int TH    = 32;
constexpr int NPERS = 1280;                // persistent blocks
// tiles = 8 x 16 x 48 = 6144; bc0 = bid>>7 in [0,10); bc += 10 per iter

constexpr int HTP   = 56;                  // Ht pitch (halves)
constexpr int HTQS  = 64 * HTP;            // 3584 halves per plane
constexpr int SMEMH = 4 * HTQS;            // 14336 halves = 28,672 B

constexpr float C1 = 1.0e-4f;
constexpr float C2 = 9.0e-4f;

// Normalized gaussian g[d] = exp(-(d-5)^2/4.5)/sum, f32-rounded.
__device__ const float GW[11] = {
    0.00102838f, 0.00759876f, 0.03600077f, 0.10936070f, 0.21300553f,
    0.26601172f, 0.21300553f, 0.10936070f, 0.03600077f, 0.00759876f,
    0.00102838f};

__device__ __forceinline__ h8 ldfrag(const f16* __restrict__ gtab, int base) {
    h8 b;
#pragma unroll
    for (int i = 0; i < 8; ++i) b[i] = gtab[base + i];
    return b;
}

__global__ __launch_bounds__(64) void ssim_init(double* acc) {
    if (threadIdx.x == 0) acc[0] = 0.0;
}

__global__ __launch_bounds__(256, 4) void ssim_main(const float* __restrict__ sr,
                                                    const float* __restrict__ hr,
                                                    double* __restrict__ sink,
                                                    int mode) {
    __shared__ __align__(16) f16 smem[SMEMH];   // Ht[4][64 cols][56]
    __shared__ __align__(8)  f16 gtab[128];     // zero-padded weights, g at [66..76]
    __shared__ float wsums[4];

    const int tid  = threadIdx.x;
    const int w    = tid >> 6;
    const int lane = tid & 63;
    const int l15  = lane & 15;
    const int grp8 = (lane >> 4) << 3;
    const int grp4 = (lane >> 4) << 2;

    const int bx  = blockIdx.x & 7;
    const int by  = (blockIdx.x >> 3) & 15;
    const int bc0 = blockIdx.x >> 7;            // 0..9
    const int gr0 = by * TH - 5;
    const int gc0 = bx * TW - 8;

    // loop-invariant per-lane load geometry (clamped BOTH sides, unconditional)
    const int colh = gc0 + 16 * w + grp8;       // multiple of 8; in [-8, 512]
    const int cc   = colh < 0 ? 0 : (colh > IMG_W - 8 ? IMG_W - 8 : colh);
    const bool cok = (unsigned)colh < (unsigned)IMG_W;
    int  offc[3];                               // clamped element offsets
    bool okM[3];
#pragma unroll
    for (int Mt = 0; Mt < 3; ++Mt) {
        const int r  = gr0 + l15 + 16 * Mt;
        const int rc = r < 0 ? 0 : (r > IMG_H - 1 ? IMG_H - 1 : r);
        okM[Mt] = cok & ((unsigned)r < (unsigned)IMG_H);
        offc[Mt] = rc * IMG_W + cc;             // max 511*512+504 -> +7 < PL
    }

    // ---- g-table fill ----
    if (tid < 128) {
        const int d = tid - 66;
        float v = 0.f;
        if ((unsigned)d <= 10u) v = GW[d];
        gtab[tid] = (f16)v;
    }

    // ---- rs compensation (pure-constant f16 round-trip; == gtab values) ----
    float s16 = 0.f;
#pragma unroll
    for (int d = 0; d <= 10; ++d) s16 += (float)(f16)GW[d];
    const float rs = 1.0f / (s16 * s16);

    __syncthreads();                            // gtab ready (only pre-loop barrier)

    const h8 bh = ldfrag(gtab, 63 + grp8 - l15);   // h-conv: g[kl-l15-3]
    const h8 bv = ldfrag(gtab, 66 + grp8 - l15);   // v-conv: g[kl-l15]

    // ---- prologue: load tile bc0 into cur (unconditional clamped) ----
    float4 cA0[3], cA1[3], cB0[3], cB1[3];      // 48 VGPR
    {
        const float* __restrict__ srp = sr + (size_t)bc0 * PL;
        const float* __restrict__ hrp = hr + (size_t)bc0 * PL;
#pragma unroll
        for (int Mt = 0; Mt < 3; ++Mt) {
            const float4* pa = (const float4*)&srp[offc[Mt]];
            const float4* pb = (const float4*)&hrp[offc[Mt]];
            cA0[Mt] = pa[0]; cA1[Mt] = pa[1];
            cB0[Mt] = pb[0]; cB1[Mt] = pb[1];
        }
    }

    float local = 0.f;

    for (int bc = bc0; bc < NBC; bc += 10) {
        // ---- prefetch next tile (clamped plane index; values unused on last) ----
        const int bcn = (bc + 10 < NBC) ? bc + 10 : bc;
        const float* __restrict__ srn = sr + (size_t)bcn * PL;
        const float* __restrict__ hrn = hr + (size_t)bcn * PL;
        float4 nA0[3], nA1[3], nB0[3], nB1[3];
#pragma unroll
        for (int Mt = 0; Mt < 3; ++Mt) {
            const float4* pa = (const float4*)&srn[offc[Mt]];
            const float4* pb = (const float4*)&hrn[offc[Mt]];
            nA0[Mt] = pa[0]; nA1[Mt] = pa[1];
            nB0[Mt] = pb[0]; nB1[Mt] = pb[1];
        }
        __builtin_amdgcn_sched_barrier(0);      // pin prefetch issue here

        // ---- h-conv + immediate transpose-store, per M-tile ----
        const int cbase = (16 * w + l15) * HTP;
#pragma unroll
        for (int Mt = 0; Mt < 3; ++Mt) {
            float4 a0 = cA0[Mt], a1 = cA1[Mt], b0 = cB0[Mt], b1 = cB1[Mt];
            if (!okM[Mt]) {                     // zero-mask OOB lanes
                a0 = a1 = b0 = b1 = (float4){0.f, 0.f, 0.f, 0.f};
            }
            const f32x2* A0 = (const f32x2*)&a0;
            const f32x2* A1 = (const f32x2*)&a1;
            const f32x2* B0 = (const f32x2*)&b0;
            const f32x2* B1 = (const f32x2*)&b1;
            const f32x2 s0 = A0[0] * A0[0] + B0[0] * B0[0];
            const f32x2 s1 = A0[1] * A0[1] + B0[1] * B0[1];
            const f32x2 s2 = A1[0] * A1[0] + B1[0] * B1[0];
            const f32x2 s3 = A1[1] * A1[1] + B1[1] * B1[1];
            const f32x2 p0 = A0[0] * B0[0], p1 = A0[1] * B0[1];
            const f32x2 p2 = A1[0] * B1[0], p3 = A1[1] * B1[1];
            union { h2v h2[4]; h8 v; } fa, fb, fs, fp;
            fa.h2[0] = __builtin_amdgcn_cvt_pkrtz(A0[0].x, A0[0].y);
            fa.h2[1] = __builtin_amdgcn_cvt_pkrtz(A0[1].x, A0[1].y);
            fa.h2[2] = __builtin_amdgcn_cvt_pkrtz(A1[0].x, A1[0].y);
            fa.h2[3] = __builtin_amdgcn_cvt_pkrtz(A1[1].x, A1[1].y);
            fb.h2[0] = __builtin_amdgcn_cvt_pkrtz(B0[0].x, B0[0].y);
            fb.h2[1] = __builtin_amdgcn_cvt_pkrtz(B0[1].x, B0[1].y);
            fb.h2[2] = __builtin_amdgcn_cvt_pkrtz(B1[0].x, B1[0].y);
            fb.h2[3] = __builtin_amdgcn_cvt_pkrtz(B1[1].x, B1[1].y);
            fs.h2[0] = __builtin_amdgcn_cvt_pkrtz(s0.x, s0.y);
            fs.h2[1] = __builtin_amdgcn_cvt_pkrtz(s1.x, s1.y);
            fs.h2[2] = __builtin_amdgcn_cvt_pkrtz(s2.x, s2.y);
            fs.h2[3] = __builtin_amdgcn_cvt_pkrtz(s3.x, s3.y);
            fp.h2[0] = __builtin_amdgcn_cvt_pkrtz(p0.x, p0.y);
            fp.h2[1] = __builtin_amdgcn_cvt_pkrtz(p1.x, p1.y);
            fp.h2[2] = __builtin_amdgcn_cvt_pkrtz(p2.x, p2.y);
            fp.h2[3] = __builtin_amdgcn_cvt_pkrtz(p3.x, p3.y);
            const f32x4 z = {0.f, 0.f, 0.f, 0.f};
            f32x4 acc_a = __builtin_amdgcn_mfma_f32_16x16x32_f16(fa.v, bh, z, 0, 0, 0);
            f32x4 acc_b = __builtin_amdgcn_mfma_f32_16x16x32_f16(fb.v, bh, z, 0, 0, 0);
            f32x4 acc_s = __builtin_amdgcn_mfma_f32_16x16x32_f16(fs.v, bh, z, 0, 0, 0);
            f32x4 acc_p = __builtin_amdgcn_mfma_f32_16x16x32_f16(fp.v, bh, z, 0, 0, 0);
            union { h2v h2[2]; h4 v; } u;
            u.h2[0] = __builtin_amdgcn_cvt_pkrtz(acc_a[0], acc_a[1]);
            u.h2[1] = __builtin_amdgcn_cvt_pkrtz(acc_a[2], acc_a[3]);
            *(h4*)&smem[0 * HTQS + cbase + 16 * Mt + grp4] = u.v;
            u.h2[0] = __builtin_amdgcn_cvt_pkrtz(acc_b[0], acc_b[1]);
            u.h2[1] = __builtin_amdgcn_cvt_pkrtz(acc_b[2], acc_b[3]);
            *(h4*)&smem[1 * HTQS + cbase + 16 * Mt + grp4] = u.v;
            u.h2[0] = __builtin_amdgcn_cvt_pkrtz(acc_s[0], acc_s[1]);
            u.h2[1] = __builtin_amdgcn_cvt_pkrtz(acc_s[2], acc_s[3]);
            *(h4*)&smem[2 * HTQS + cbase + 16 * Mt + grp4] = u.v;
            u.h2[0] = __builtin_amdgcn_cvt_pkrtz(acc_p[0], acc_p[1]);
            u.h2[1] = __builtin_amdgcn_cvt_pkrtz(acc_p[2], acc_p[3]);
            *(h4*)&smem[3 * HTQS + cbase + 16 * Mt + grp4] = u.v;
        }

        // ---- v-conv (wave-own Ht cols; same-wave RAW in-order; no barrier) ----
        f32x4 acc2[4][2];
#pragma unroll
        for (int q = 0; q < 4; ++q) {
            const h8 a0 = *(const h8*)&smem[q * HTQS + cbase + grp8];       // j 0..31
            const h8 a1 = *(const h8*)&smem[q * HTQS + cbase + grp8 + 16];  // j 16..47
            const f32x4 z = {0.f, 0.f, 0.f, 0.f};
            acc2[q][0] = __builtin_amdgcn_mfma_f32_16x16x32_f16(a0, bv, z, 0, 0, 0);
            acc2[q][1] = __builtin_amdgcn_mfma_f32_16x16x32_f16(a1, bv, z, 0, 0, 0);
        }

        // ---- SSIM map on D2 (8 px/thread) ----
#pragma unroll
        for (int nt = 0; nt < 2; ++nt) {
            const f32x4 m1 = acc2[0][nt] * rs;
            const f32x4 m2 = acc2[1][nt] * rs;
            const f32x4 S  = acc2[2][nt] * rs;   // E[a^2+b^2]
            const f32x4 pp = acc2[3][nt] * rs;   // E[ab]
            const f32x4 mu1s = m1 * m1, mu2s = m2 * m2, mu12 = m1 * m2;
            const f32x4 sg12 = pp - mu12;
            const f32x4 sgs  = S - mu1s - mu2s;
            const f32x4 num = (2.f * mu12 + C1) * (2.f * sg12 + C2);
            const f32x4 den = (mu1s + mu2s + C1) * (sgs + C2) + 1e-12f;
#pragma unroll
            for (int e = 0; e < 4; ++e)
                local += num[e] * __builtin_amdgcn_rcpf(den[e]);
        }

        // ---- rotate prefetched regs into cur ----
#pragma unroll
        for (int Mt = 0; Mt < 3; ++Mt) {
            cA0[Mt] = nA0[Mt]; cA1[Mt] = nA1[Mt];
            cB0[Mt] = nB0[Mt]; cB1[Mt] = nB1[Mt];
        }
    }

    // ---- block reduction ----
#pragma unroll
    for (int offr = 32; offr > 0; offr >>= 1)
        local += __shfl_down(local, offr, 64);
    if ((tid & 63) == 0) wsums[tid >> 6] = local;
    __syncthreads();
    if (tid == 0) {
        const double bsum = (double)(wsums[0] + wsums[1] + wsums[2] + wsums[3]);
        if (mode == 0) {
            sink[blockIdx.x] = bsum;
        } else {
            atomicAdd(sink, bsum);
        }
    }
}

__global__ __launch_bounds__(256) void ssim_finalize(const double* __restrict__ partial,
                                                     float* __restrict__ out, int count) {
    __shared__ double ws[4];
    double s = 0.0;
    for (int i = threadIdx.x; i < count; i += 256) s += partial[i];
#pragma unroll
    for (int off = 32; off > 0; off >>= 1)
        s += __shfl_down(s, off, 64);
    const int lane = threadIdx.x & 63, wave = threadIdx.x >> 6;
    if (lane == 0) ws[wave] = s;
    __syncthreads();
    if (threadIdx.x == 0) {
        const double tot = ws[0] + ws[1] + ws[2] + ws[3];
        const double n = (double)NBC * IMG_H * IMG_W;
        out[0] = (float)(1.0 - tot / n);
    }
}

extern "C" void kernel_launch(void* const* d_in, const int* in_sizes, int n_in,
                              void* d_out, int out_size, void* d_ws, size_t ws_size,
                              hipStream_t stream) {
    const float* sr = (const float*)d_in[0];
    const float* hr = (const float*)d_in[1];
    float* out = (float*)d_out;

    if (ws_size >= (size_t)NPERS * sizeof(double)) {
        double* partial = (double*)d_ws; // fully overwritten each call
        ssim_main<<<dim3(NPERS), dim3(256), 0, stream>>>(sr, hr, partial, 0);
        ssim_finalize<<<dim3(1), dim3(256), 0, stream>>>(partial, out, NPERS);
    } else {
        double* acc = (double*)d_ws;
        ssim_init<<<dim3(1), dim3(64), 0, stream>>>(acc);
        ssim_main<<<dim3(NPERS), dim3(256), 0, stream>>>(sr, hr, acc, 1);
        ssim_finalize<<<dim3(1), dim3(256), 0, stream>>>(acc, out, 1);
    }
}

// Round 14
// 136.615 us; speedup vs baseline: 1.2094x; 1.2094x over previous
//
#include <hip/hip_runtime.h>

// SSIM loss, R16. R15 post-mortem: 75.8 us — VGPR_Count=64 + WRITE_SIZE 33MB
// = the allocator SPILLED the 48-VGPR cross-tile prefetch to scratch (3rd
// defeat of long-lived register prefetch: R10 sank, R15 spilled). Lesson:
// cross-tile bulk prefetch is uncontrollable from HIP source here.
// R16: within-tile fix of R13's serialization, zero cross-tile liveness.
//  - all 12 current-tile float4 loads issued UNCONDITIONALLY (both-side
//    clamped addrs) in ONE cluster at tile top + sched_barrier(0) pin;
//    consume Mt0/Mt1/Mt2 in order -> compiler stages vmcnt(8/4/0): ~1
//    exposed latency round per tile instead of 3 (stall/issue ~1.3 -> 3
//    waves/SIMD hides it; we have 3+).
//  - live ranges end within the tile -> no spill pressure (~85 peak VGPR).
//  - OOB lanes zero-masked at frag build (identical arithmetic).
// Retained from R13/R15: no X staging, Ht-only LDS (HTP=56), wave-decoupled
// ZERO in-loop barriers, per-Mt immediate transpose-store, one-k-step band
// MFMA, LDS g-table, rs compensation, persistent 1280 blocks, bc += 10.

typedef __attribute__((ext_vector_type(2))) float  f32x2;
typedef __attribute__((ext_vector_type(4))) float  f32x4;
typedef __fp16 f16;
typedef __attribute__((ext_vector_type(2))) __fp16 h2v;
typedef __attribute__((ext_vector_type(4))) __fp16 h4;
typedef __attribute__((ext_vector_type(8))) __fp16 h8;

constexpr int IMG_H = 512;
constexpr int IMG_W = 512;
constexpr int PL    = IMG_H * IMG_W;
constexpr int NBC   = 48;
constexpr int TW    = 64;
constexpr int TH    = 32;
constexpr int NPERS = 1280;                // persistent blocks
// tiles = 8 x 16 x 48 = 6144; bc0 = bid>>7 in [0,10); bc += 10 per iter

constexpr int HTP   = 56;                  // Ht pitch (halves)
constexpr int HTQS  = 64 * HTP;            // 3584 halves per plane
constexpr int SMEMH = 4 * HTQS;            // 14336 halves = 28,672 B

constexpr float C1 = 1.0e-4f;
constexpr float C2 = 9.0e-4f;

// Normalized gaussian g[d] = exp(-(d-5)^2/4.5)/sum, f32-rounded.
__device__ const float GW[11] = {
    0.00102838f, 0.00759876f, 0.03600077f, 0.10936070f, 0.21300553f,
    0.26601172f, 0.21300553f, 0.10936070f, 0.03600077f, 0.00759876f,
    0.00102838f};

__device__ __forceinline__ h8 ldfrag(const f16* __restrict__ gtab, int base) {
    h8 b;
#pragma unroll
    for (int i = 0; i < 8; ++i) b[i] = gtab[base + i];
    return b;
}

__global__ __launch_bounds__(64) void ssim_init(double* acc) {
    if (threadIdx.x == 0) acc[0] = 0.0;
}

__global__ __launch_bounds__(256, 4) void ssim_main(const float* __restrict__ sr,
                                                    const float* __restrict__ hr,
                                                    double* __restrict__ sink,
                                                    int mode) {
    __shared__ __align__(16) f16 smem[SMEMH];   // Ht[4][64 cols][56]
    __shared__ __align__(8)  f16 gtab[128];     // zero-padded weights, g at [66..76]
    __shared__ float wsums[4];

    const int tid  = threadIdx.x;
    const int w    = tid >> 6;
    const int lane = tid & 63;
    const int l15  = lane & 15;
    const int grp8 = (lane >> 4) << 3;
    const int grp4 = (lane >> 4) << 2;

    const int bx  = blockIdx.x & 7;
    const int by  = (blockIdx.x >> 3) & 15;
    const int bc0 = blockIdx.x >> 7;            // 0..9
    const int gr0 = by * TH - 5;
    const int gc0 = bx * TW - 8;

    // loop-invariant per-lane load geometry (clamped BOTH sides, unconditional)
    const int colh = gc0 + 16 * w + grp8;       // multiple of 8; in [-8, 512]
    const int cc   = colh < 0 ? 0 : (colh > IMG_W - 8 ? IMG_W - 8 : colh);
    const bool cok = (unsigned)colh < (unsigned)IMG_W;
    int  offc[3];                               // clamped element offsets
    bool okM[3];
#pragma unroll
    for (int Mt = 0; Mt < 3; ++Mt) {
        const int r  = gr0 + l15 + 16 * Mt;
        const int rc = r < 0 ? 0 : (r > IMG_H - 1 ? IMG_H - 1 : r);
        okM[Mt] = cok & ((unsigned)r < (unsigned)IMG_H);
        offc[Mt] = rc * IMG_W + cc;             // max 511*512+504 -> +7 < PL
    }

    // ---- g-table fill ----
    if (tid < 128) {
        const int d = tid - 66;
        float v = 0.f;
        if ((unsigned)d <= 10u) v = GW[d];
        gtab[tid] = (f16)v;
    }

    // ---- rs compensation (pure-constant f16 round-trip; == gtab values) ----
    float s16 = 0.f;
#pragma unroll
    for (int d = 0; d <= 10; ++d) s16 += (float)(f16)GW[d];
    const float rs = 1.0f / (s16 * s16);

    __syncthreads();                            // gtab ready (only pre-loop barrier)

    const h8 bh = ldfrag(gtab, 63 + grp8 - l15);   // h-conv: g[kl-l15-3]
    const h8 bv = ldfrag(gtab, 66 + grp8 - l15);   // v-conv: g[kl-l15]

    float local = 0.f;

    for (int bc = bc0; bc < NBC; bc += 10) {
        const float* __restrict__ srp = sr + (size_t)bc * PL;
        const float* __restrict__ hrp = hr + (size_t)bc * PL;

        // ---- issue ALL 12 tile loads in one cluster (short live ranges) ----
        float4 A0[3], A1[3], B0[3], B1[3];
#pragma unroll
        for (int Mt = 0; Mt < 3; ++Mt) {
            const float4* pa = (const float4*)&srp[offc[Mt]];
            const float4* pb = (const float4*)&hrp[offc[Mt]];
            A0[Mt] = pa[0]; A1[Mt] = pa[1];
            B0[Mt] = pb[0]; B1[Mt] = pb[1];
        }
        __builtin_amdgcn_sched_barrier(0);      // loads may not sink past here

        // ---- h-conv + immediate transpose-store, per M-tile ----
        const int cbase = (16 * w + l15) * HTP;
#pragma unroll
        for (int Mt = 0; Mt < 3; ++Mt) {
            float4 a0 = A0[Mt], a1 = A1[Mt], b0 = B0[Mt], b1 = B1[Mt];
            if (!okM[Mt]) {                     // zero-mask OOB lanes
                a0 = a1 = b0 = b1 = (float4){0.f, 0.f, 0.f, 0.f};
            }
            const f32x2* pA0 = (const f32x2*)&a0;
            const f32x2* pA1 = (const f32x2*)&a1;
            const f32x2* pB0 = (const f32x2*)&b0;
            const f32x2* pB1 = (const f32x2*)&b1;
            const f32x2 s0 = pA0[0] * pA0[0] + pB0[0] * pB0[0];
            const f32x2 s1 = pA0[1] * pA0[1] + pB0[1] * pB0[1];
            const f32x2 s2 = pA1[0] * pA1[0] + pB1[0] * pB1[0];
            const f32x2 s3 = pA1[1] * pA1[1] + pB1[1] * pB1[1];
            const f32x2 p0 = pA0[0] * pB0[0], p1 = pA0[1] * pB0[1];
            const f32x2 p2 = pA1[0] * pB1[0], p3 = pA1[1] * pB1[1];
            union { h2v h2[4]; h8 v; } fa, fb, fs, fp;
            fa.h2[0] = __builtin_amdgcn_cvt_pkrtz(pA0[0].x, pA0[0].y);
            fa.h2[1] = __builtin_amdgcn_cvt_pkrtz(pA0[1].x, pA0[1].y);
            fa.h2[2] = __builtin_amdgcn_cvt_pkrtz(pA1[0].x, pA1[0].y);
            fa.h2[3] = __builtin_amdgcn_cvt_pkrtz(pA1[1].x, pA1[1].y);
            fb.h2[0] = __builtin_amdgcn_cvt_pkrtz(pB0[0].x, pB0[0].y);
            fb.h2[1] = __builtin_amdgcn_cvt_pkrtz(pB0[1].x, pB0[1].y);
            fb.h2[2] = __builtin_amdgcn_cvt_pkrtz(pB1[0].x, pB1[0].y);
            fb.h2[3] = __builtin_amdgcn_cvt_pkrtz(pB1[1].x, pB1[1].y);
            fs.h2[0] = __builtin_amdgcn_cvt_pkrtz(s0.x, s0.y);
            fs.h2[1] = __builtin_amdgcn_cvt_pkrtz(s1.x, s1.y);
            fs.h2[2] = __builtin_amdgcn_cvt_pkrtz(s2.x, s2.y);
            fs.h2[3] = __builtin_amdgcn_cvt_pkrtz(s3.x, s3.y);
            fp.h2[0] = __builtin_amdgcn_cvt_pkrtz(p0.x, p0.y);
            fp.h2[1] = __builtin_amdgcn_cvt_pkrtz(p1.x, p1.y);
            fp.h2[2] = __builtin_amdgcn_cvt_pkrtz(p2.x, p2.y);
            fp.h2[3] = __builtin_amdgcn_cvt_pkrtz(p3.x, p3.y);
            const f32x4 z = {0.f, 0.f, 0.f, 0.f};
            f32x4 acc_a = __builtin_amdgcn_mfma_f32_16x16x32_f16(fa.v, bh, z, 0, 0, 0);
            f32x4 acc_b = __builtin_amdgcn_mfma_f32_16x16x32_f16(fb.v, bh, z, 0, 0, 0);
            f32x4 acc_s = __builtin_amdgcn_mfma_f32_16x16x32_f16(fs.v, bh, z, 0, 0, 0);
            f32x4 acc_p = __builtin_amdgcn_mfma_f32_16x16x32_f16(fp.v, bh, z, 0, 0, 0);
            union { h2v h2[2]; h4 v; } u;
            u.h2[0] = __builtin_amdgcn_cvt_pkrtz(acc_a[0], acc_a[1]);
            u.h2[1] = __builtin_amdgcn_cvt_pkrtz(acc_a[2], acc_a[3]);
            *(h4*)&smem[0 * HTQS + cbase + 16 * Mt + grp4] = u.v;
            u.h2[0] = __builtin_amdgcn_cvt_pkrtz(acc_b[0], acc_b[1]);
            u.h2[1] = __builtin_amdgcn_cvt_pkrtz(acc_b[2], acc_b[3]);
            *(h4*)&smem[1 * HTQS + cbase + 16 * Mt + grp4] = u.v;
            u.h2[0] = __builtin_amdgcn_cvt_pkrtz(acc_s[0], acc_s[1]);
            u.h2[1] = __builtin_amdgcn_cvt_pkrtz(acc_s[2], acc_s[3]);
            *(h4*)&smem[2 * HTQS + cbase + 16 * Mt + grp4] = u.v;
            u.h2[0] = __builtin_amdgcn_cvt_pkrtz(acc_p[0], acc_p[1]);
            u.h2[1] = __builtin_amdgcn_cvt_pkrtz(acc_p[2], acc_p[3]);
            *(h4*)&smem[3 * HTQS + cbase + 16 * Mt + grp4] = u.v;
        }

        // ---- v-conv (wave-own Ht cols; same-wave RAW in-order; no barrier) ----
        f32x4 acc2[4][2];
#pragma unroll
        for (int q = 0; q < 4; ++q) {
            const h8 a0 = *(const h8*)&smem[q * HTQS + cbase + grp8];       // j 0..31
            const h8 a1 = *(const h8*)&smem[q * HTQS + cbase + grp8 + 16];  // j 16..47
            const f32x4 z = {0.f, 0.f, 0.f, 0.f};
            acc2[q][0] = __builtin_amdgcn_mfma_f32_16x16x32_f16(a0, bv, z, 0, 0, 0);
            acc2[q][1] = __builtin_amdgcn_mfma_f32_16x16x32_f16(a1, bv, z, 0, 0, 0);
        }

        // ---- SSIM map on D2 (8 px/thread) ----
#pragma unroll
        for (int nt = 0; nt < 2; ++nt) {
            const f32x4 m1 = acc2[0][nt] * rs;
            const f32x4 m2 = acc2[1][nt] * rs;
            const f32x4 S  = acc2[2][nt] * rs;   // E[a^2+b^2]
            const f32x4 pp = acc2[3][nt] * rs;   // E[ab]
            const f32x4 mu1s = m1 * m1, mu2s = m2 * m2, mu12 = m1 * m2;
            const f32x4 sg12 = pp - mu12;
            const f32x4 sgs  = S - mu1s - mu2s;
            const f32x4 num = (2.f * mu12 + C1) * (2.f * sg12 + C2);
            const f32x4 den = (mu1s + mu2s + C1) * (sgs + C2) + 1e-12f;
#pragma unroll
            for (int e = 0; e < 4; ++e)
                local += num[e] * __builtin_amdgcn_rcpf(den[e]);
        }
    }

    // ---- block reduction ----
#pragma unroll
    for (int offr = 32; offr > 0; offr >>= 1)
        local += __shfl_down(local, offr, 64);
    if ((tid & 63) == 0) wsums[tid >> 6] = local;
    __syncthreads();
    if (tid == 0) {
        const double bsum = (double)(wsums[0] + wsums[1] + wsums[2] + wsums[3]);
        if (mode == 0) {
            sink[blockIdx.x] = bsum;
        } else {
            atomicAdd(sink, bsum);
        }
    }
}

__global__ __launch_bounds__(256) void ssim_finalize(const double* __restrict__ partial,
                                                     float* __restrict__ out, int count) {
    __shared__ double ws[4];
    double s = 0.0;
    for (int i = threadIdx.x; i < count; i += 256) s += partial[i];
#pragma unroll
    for (int off = 32; off > 0; off >>= 1)
        s += __shfl_down(s, off, 64);
    const int lane = threadIdx.x & 63, wave = threadIdx.x >> 6;
    if (lane == 0) ws[wave] = s;
    __syncthreads();
    if (threadIdx.x == 0) {
        const double tot = ws[0] + ws[1] + ws[2] + ws[3];
        const double n = (double)NBC * IMG_H * IMG_W;
        out[0] = (float)(1.0 - tot / n);
    }
}

extern "C" void kernel_launch(void* const* d_in, const int* in_sizes, int n_in,
                              void* d_out, int out_size, void* d_ws, size_t ws_size,
                              hipStream_t stream) {
    const float* sr = (const float*)d_in[0];
    const float* hr = (const float*)d_in[1];
    float* out = (float*)d_out;

    if (ws_size >= (size_t)NPERS * sizeof(double)) {
        double* partial = (double*)d_ws; // fully overwritten each call
        ssim_main<<<dim3(NPERS), dim3(256), 0, stream>>>(sr, hr, partial, 0);
        ssim_finalize<<<dim3(1), dim3(256), 0, stream>>>(partial, out, NPERS);
    } else {
        double* acc = (double*)d_ws;
        ssim_init<<<dim3(1), dim3(64), 0, stream>>>(acc);
        ssim_main<<<dim3(NPERS), dim3(256), 0, stream>>>(sr, hr, acc, 1);
        ssim_finalize<<<dim3(1), dim3(256), 0, stream>>>(acc, out, 1);
    }
}